// Round 8
// baseline (26.582 us; speedup 1.0000x reference)
//
#include <hip/hip_runtime.h>
#include <hip/hip_bf16.h>
#include <math.h>

// Quanvolution via Pauli back-propagation (derivation R1, validated R1-R6):
//  alpha_q = theta_q + w0_q; A..D = cos(alpha_q), a..d = sin(alpha_q):
//   z0 = K0*A  + K1*ab
//   z1 = K2*B  + K3*A*bc + K4*ac
//   z2 = K5*AC + K6*B*cd + K7*A*bd + K8*ab*C + K9*ad
//   z3 = L1*BD + L2*AC*d + L3*Bc + L4*Ab*cD + L5*Ab + L6*ab*Cd + L7*ac*D + L8*a
//
// R7: split into two streaming dispatches to decouple (and measure) the
// phases. A: patch -> bf16 feats in d_ws (memory-bound, coalesced).
// B: [B,784]x[784,10] GEMM + log_softmax, 4 images/wave W-amortized.
#define INV2PI 0.15915494309189535f

__device__ __forceinline__ float rfl(float v) {
    return __int_as_float(__builtin_amdgcn_readfirstlane(__float_as_int(v)));
}

struct KL { float K0,K1,K2,K3,K4,K5,K6,K7,K8,K9,L1,L2,L3,L4,L5,L6,L7,L8; };

__device__ __forceinline__ KL make_kl(const float* wts, float* w0r) {
    float cw1[4], sw1[4];
#pragma unroll
    for (int q = 0; q < 4; ++q) {
        w0r[q] = rfl(wts[q] * INV2PI);
        float r = wts[4 + q] * INV2PI;
        r -= floorf(r);
        cw1[q] = __builtin_amdgcn_cosf(r);
        sw1[q] = __builtin_amdgcn_sinf(r);
    }
    const float cc  = cw1[0]*cw1[1], cs = cw1[0]*sw1[1];
    const float sc  = sw1[0]*cw1[1], ss = sw1[0]*sw1[1];
    const float ccc = cc*cw1[2], ccs = cc*sw1[2], csc = cs*cw1[2], css = cs*sw1[2];
    const float scc = sc*cw1[2], ssc = ss*cw1[2], sss = ss*sw1[2];
    KL k;
    k.K0 = rfl(cw1[0]);      k.K1 = rfl(-sw1[0]);
    k.K2 = rfl(cc);          k.K3 = rfl(-cs);         k.K4 = rfl(ss);
    k.K5 = rfl(ccc);         k.K6 = rfl(-ccs);        k.K7 = rfl(css);
    k.K8 = rfl(-scc);        k.K9 = rfl(-sss);
    k.L1 = rfl(ccc*cw1[3]);  k.L2 = rfl(-ccc*sw1[3]);
    k.L3 = rfl(ccs*sw1[3]);  k.L4 = rfl(-csc*cw1[3]);
    k.L5 = rfl(-css*sw1[3]); k.L6 = rfl(scc*sw1[3]);
    k.L7 = rfl(ssc*cw1[3]);  k.L8 = rfl(sss*sw1[3]);
    return k;
}

// ---------------- Kernel A: patches -> bf16 feats ----------------
__global__ __launch_bounds__(256) void quanv_feat_kernel(
    const float* __restrict__ x,        // [B, 784]
    const float* __restrict__ wts,      // [2, 4]
    __hip_bfloat16* __restrict__ feats, // [B*196*4]
    int NP)                             // B*196
{
    const int pid = blockIdx.x * 256 + threadIdx.x;
    if (pid >= NP) return;

    float w0r[4];
    const KL k = make_kl(wts, w0r);

    const int img = pid / 196;
    const int pl  = pid - img * 196;
    const int pi  = pl / 14, pj = pl - pi * 14;
    const float* xp = x + (size_t)img * 784 + pi * 56 + pj * 2;
    const float2 t0 = *(const float2*)xp;
    const float2 t1 = *(const float2*)(xp + 28);

    float r;
    r = fmaf(t0.x, INV2PI, w0r[0]); r -= floorf(r);
    const float a  = __builtin_amdgcn_sinf(r), A  = __builtin_amdgcn_cosf(r);
    r = fmaf(t0.y, INV2PI, w0r[1]); r -= floorf(r);
    const float b  = __builtin_amdgcn_sinf(r), Bv = __builtin_amdgcn_cosf(r);
    r = fmaf(t1.x, INV2PI, w0r[2]); r -= floorf(r);
    const float c  = __builtin_amdgcn_sinf(r), C  = __builtin_amdgcn_cosf(r);
    r = fmaf(t1.y, INV2PI, w0r[3]); r -= floorf(r);
    const float d  = __builtin_amdgcn_sinf(r), D  = __builtin_amdgcn_cosf(r);

    const float ab=a*b, bc=b*c, ac=a*c, cd=c*d, bd=b*d, ad=a*d;
    const float AC=A*C, Ab=A*b, Bc=Bv*c, BD=Bv*D, cD=c*D, Cd=C*d;

    const float z0 = fmaf(k.K0, A,  k.K1*ab);
    const float z1 = fmaf(k.K2, Bv, fmaf(k.K3, A*bc, k.K4*ac));
    const float z2 = fmaf(k.K5, AC, fmaf(k.K6, Bv*cd,
                     fmaf(k.K7, A*bd, fmaf(k.K8, ab*C, k.K9*ad))));
    const float z3 = fmaf(k.L1, BD, fmaf(k.L2, AC*d, fmaf(k.L3, Bc,
                     fmaf(k.L4, Ab*cD, fmaf(k.L5, Ab, fmaf(k.L6, ab*Cd,
                     fmaf(k.L7, ac*D, k.L8*a)))))));

    // pack 4 bf16 (RNE) -> 8B coalesced store
    union { ushort4 u; __hip_bfloat16 h[4]; } pk;
    pk.h[0] = __float2bfloat16(z0);
    pk.h[1] = __float2bfloat16(z1);
    pk.h[2] = __float2bfloat16(z2);
    pk.h[3] = __float2bfloat16(z3);
    *(ushort4*)(feats + (size_t)pid * 4) = pk.u;
}

// ---------------- Kernel B: GEMM + log_softmax ----------------
__device__ __forceinline__ float bf2f(unsigned short u) {
    return __uint_as_float(((unsigned int)u) << 16);
}

__global__ __launch_bounds__(256) void quanv_gemm_kernel(
    const __hip_bfloat16* __restrict__ feats, // [B*784] bf16
    const float* __restrict__ W,              // [10, 784]
    const float* __restrict__ bias,           // [10]
    float* __restrict__ out,                  // [B, 10]
    int B)
{
    const int lane  = threadIdx.x & 63;
    const int img0  = (blockIdx.x * 4 + (threadIdx.x >> 6)) * 4;  // 4 imgs/wave
    if (img0 >= B) return;

    float acc[4][10];
#pragma unroll
    for (int im = 0; im < 4; ++im)
#pragma unroll
        for (int cl = 0; cl < 10; ++cl) acc[im][cl] = 0.f;

#pragma unroll
    for (int i = 0; i < 4; ++i) {
        const int p = i * 64 + lane;           // k-chunk (4 floats) index
        if (p < 196) {
            // feats: 4 imgs x ushort4 (independent loads, deep ILP)
            ushort4 f[4];
#pragma unroll
            for (int im = 0; im < 4; ++im)
                f[im] = *(const ushort4*)(feats + ((size_t)(img0 + im) * 196 + p) * 4);
#pragma unroll
            for (int cl = 0; cl < 10; ++cl) {
                const float4 wv = *(const float4*)(W + cl * 784 + p * 4);
#pragma unroll
                for (int im = 0; im < 4; ++im)
                    acc[im][cl] = fmaf(bf2f(f[im].x), wv.x, fmaf(bf2f(f[im].y), wv.y,
                                  fmaf(bf2f(f[im].z), wv.z, fmaf(bf2f(f[im].w), wv.w,
                                  acc[im][cl]))));
            }
        }
    }

#pragma unroll
    for (int im = 0; im < 4; ++im) {
        if (img0 + im < B) {
            float lg[10];
#pragma unroll
            for (int cl = 0; cl < 10; ++cl) {
                float v = acc[im][cl];
                v += __shfl_xor(v, 1, 64);
                v += __shfl_xor(v, 2, 64);
                v += __shfl_xor(v, 4, 64);
                v += __shfl_xor(v, 8, 64);
                v += __shfl_xor(v, 16, 64);
                v += __shfl_xor(v, 32, 64);
                lg[cl] = v + bias[cl];
            }
            float m = lg[0];
#pragma unroll
            for (int cl = 1; cl < 10; ++cl) m = fmaxf(m, lg[cl]);
            float s = 0.f;
#pragma unroll
            for (int cl = 0; cl < 10; ++cl) s += __expf(lg[cl] - m);
            const float lse = m + __logf(s);
            if (lane == 0) {
                float* op = out + (size_t)(img0 + im) * 10;
                *(float2*)(op + 0) = make_float2(lg[0] - lse, lg[1] - lse);
                *(float2*)(op + 2) = make_float2(lg[2] - lse, lg[3] - lse);
                *(float2*)(op + 4) = make_float2(lg[4] - lse, lg[5] - lse);
                *(float2*)(op + 6) = make_float2(lg[6] - lse, lg[7] - lse);
                *(float2*)(op + 8) = make_float2(lg[8] - lse, lg[9] - lse);
            }
        }
    }
}

extern "C" void kernel_launch(void* const* d_in, const int* in_sizes, int n_in,
                              void* d_out, int out_size, void* d_ws, size_t ws_size,
                              hipStream_t stream) {
    const float* x    = (const float*)d_in[0];
    const float* wts  = (const float*)d_in[1];
    const float* W    = (const float*)d_in[2];
    const float* bias = (const float*)d_in[3];
    float* out        = (float*)d_out;
    __hip_bfloat16* feats = (__hip_bfloat16*)d_ws;   // B*196*4 bf16 = 12.8 MB

    const int B  = in_sizes[0] / 784;
    const int NP = B * 196;

    quanv_feat_kernel<<<(NP + 255) / 256, 256, 0, stream>>>(x, wts, feats, NP);
    quanv_gemm_kernel<<<(B + 15) / 16, 256, 0, stream>>>(feats, W, bias, out, B);
}

// Round 9
// 19.883 us; speedup vs baseline: 1.3369x; 1.3369x over previous
//
#include <hip/hip_runtime.h>
#include <math.h>

// Quanvolution via Pauli back-propagation (derivation R1, validated R1-R7):
//  alpha_q = theta_q + w0_q; A..D = cos(alpha_q), a..d = sin(alpha_q):
//   z0 = K0*A  + K1*ab
//   z1 = K2*B  + K3*A*bc + K4*ac
//   z2 = K5*AC + K6*B*cd + K7*A*bd + K8*ab*C + K9*ad
//   z3 = L1*BD + L2*AC*d + L3*Bc + L4*Ab*cD + L5*Ab + L6*ab*Cd + L7*ac*D + L8*a
//
// R8: 448-thread blocks (7 waves), 4 images/block. lane=(pair-slot,image):
// each lane processes one horizontally-adjacent PATCH-PAIR of one image ->
// x = two aligned float4 loads issued at kernel top (hidden under constant
// prep), one compute pass at 88% lane-util, W read once per block with 4-way
// lane broadcast, 4-level butterfly + tiny LDS tail. Single dispatch.
#define INV2PI 0.15915494309189535f

__device__ __forceinline__ float rfl(float v) {
    return __int_as_float(__builtin_amdgcn_readfirstlane(__float_as_int(v)));
}

__global__ __launch_bounds__(448) void quanv_pair_kernel(
    const float* __restrict__ x,     // [B, 784]
    const float* __restrict__ wts,   // [2, 4]
    const float* __restrict__ W,     // [10, 784]
    const float* __restrict__ bias,  // [10]
    float* __restrict__ out,         // [B, 10]
    int B)
{
    __shared__ float part[7][4][10];
    __shared__ float logits[4][10];

    const int tid   = threadIdx.x;
    const int wave  = tid >> 6, lane = tid & 63;
    const int im_l  = lane & 3;           // image within block
    const int pslot = lane >> 2;          // 0..15; active < 14
    const int im_g  = blockIdx.x * 4 + im_l;
    const bool act  = (pslot < 14) && (im_g < B);

    const int pair = wave * 14 + pslot;   // 0..97
    const int pi   = pair / 7;            // patch row 0..13
    const int pj   = pair - pi * 7;       // pair col 0..6 (patches 2pj, 2pj+1)

    // ---- issue both x loads FIRST (latency hides under constant prep) ----
    float4 xt = make_float4(0.f, 0.f, 0.f, 0.f), xb = xt;
    if (act) {
        const float* xp = x + (size_t)im_g * 784 + pi * 56 + pj * 4;
        xt = *(const float4*)xp;          // row 2pi, cols 4pj..4pj+3
        xb = *(const float4*)(xp + 28);   // row 2pi+1
    }

    // ---- uniform constants, pinned to SGPRs ----
    float w0r[4], cw1[4], sw1[4];
#pragma unroll
    for (int q = 0; q < 4; ++q) {
        w0r[q] = rfl(wts[q] * INV2PI);
        float r = wts[4 + q] * INV2PI;
        r -= floorf(r);
        cw1[q] = __builtin_amdgcn_cosf(r);
        sw1[q] = __builtin_amdgcn_sinf(r);
    }
    const float cc  = cw1[0]*cw1[1], cs = cw1[0]*sw1[1];
    const float sc  = sw1[0]*cw1[1], ss = sw1[0]*sw1[1];
    const float ccc = cc*cw1[2], ccs = cc*sw1[2], csc = cs*cw1[2], css = cs*sw1[2];
    const float scc = sc*cw1[2], ssc = ss*cw1[2], sss = ss*sw1[2];
    const float K0 = rfl(cw1[0]),       K1 = rfl(-sw1[0]);
    const float K2 = rfl(cc),           K3 = rfl(-cs),          K4 = rfl(ss);
    const float K5 = rfl(ccc),          K6 = rfl(-ccs),         K7 = rfl(css);
    const float K8 = rfl(-scc),         K9 = rfl(-sss);
    const float L1 = rfl(ccc*cw1[3]),   L2 = rfl(-ccc*sw1[3]);
    const float L3 = rfl(ccs*sw1[3]),   L4 = rfl(-csc*cw1[3]);
    const float L5 = rfl(-css*sw1[3]),  L6 = rfl(scc*sw1[3]);
    const float L7 = rfl(ssc*cw1[3]),   L8 = rfl(sss*sw1[3]);

    // ---- two patches for this lane ----
    float z[2][4];
#pragma unroll
    for (int h = 0; h < 2; ++h) {
        const float t0 = h ? xt.z : xt.x;
        const float t1 = h ? xt.w : xt.y;
        const float t2 = h ? xb.z : xb.x;
        const float t3 = h ? xb.w : xb.y;

        float r;
        r = fmaf(t0, INV2PI, w0r[0]); r -= floorf(r);
        const float a  = __builtin_amdgcn_sinf(r), A  = __builtin_amdgcn_cosf(r);
        r = fmaf(t1, INV2PI, w0r[1]); r -= floorf(r);
        const float b  = __builtin_amdgcn_sinf(r), Bv = __builtin_amdgcn_cosf(r);
        r = fmaf(t2, INV2PI, w0r[2]); r -= floorf(r);
        const float c  = __builtin_amdgcn_sinf(r), C  = __builtin_amdgcn_cosf(r);
        r = fmaf(t3, INV2PI, w0r[3]); r -= floorf(r);
        const float d  = __builtin_amdgcn_sinf(r), D  = __builtin_amdgcn_cosf(r);

        const float ab=a*b, bc=b*c, ac=a*c, cd=c*d, bd=b*d, ad=a*d;
        const float AC=A*C, Ab=A*b, Bc=Bv*c, BD=Bv*D, cD=c*D, Cd=C*d;

        z[h][0] = fmaf(K0, A,  K1*ab);
        z[h][1] = fmaf(K2, Bv, fmaf(K3, A*bc, K4*ac));
        z[h][2] = fmaf(K5, AC, fmaf(K6, Bv*cd,
                  fmaf(K7, A*bd, fmaf(K8, ab*C, K9*ad))));
        z[h][3] = fmaf(L1, BD, fmaf(L2, AC*d, fmaf(L3, Bc,
                  fmaf(L4, Ab*cD, fmaf(L5, Ab, fmaf(L6, ab*Cd,
                  fmaf(L7, ac*D, L8*a)))))));
    }

    // ---- GEMM: this lane's two k-chunks vs all 10 classes ----
    float acc[10];
#pragma unroll
    for (int cl = 0; cl < 10; ++cl) acc[cl] = 0.f;

    if (act) {
        const int kL = pi * 56 + pj * 8;      // (pi*14 + 2*pj)*4
#pragma unroll
        for (int cl = 0; cl < 10; ++cl) {
            const float* wp = W + cl * 784 + kL;
            const float4 wvL = *(const float4*)wp;        // patch 2pj
            const float4 wvR = *(const float4*)(wp + 4);  // patch 2pj+1
            acc[cl] = fmaf(z[0][0], wvL.x, fmaf(z[0][1], wvL.y,
                      fmaf(z[0][2], wvL.z, fmaf(z[0][3], wvL.w,
                      fmaf(z[1][0], wvR.x, fmaf(z[1][1], wvR.y,
                      fmaf(z[1][2], wvR.z, fmaf(z[1][3], wvR.w, acc[cl]))))))));
        }
    }

    // ---- butterfly over bits 2..5: lanes with same (lane&3) combine ----
#pragma unroll
    for (int cl = 0; cl < 10; ++cl) {
        float v = acc[cl];
        v += __shfl_xor(v, 4, 64);
        v += __shfl_xor(v, 8, 64);
        v += __shfl_xor(v, 16, 64);
        v += __shfl_xor(v, 32, 64);
        if (lane < 4) part[wave][lane][cl] = v;
    }
    __syncthreads();

    // ---- cross-wave sum + bias (40 threads) ----
    if (tid < 40) {
        const int im = tid / 10, cl = tid - (tid / 10) * 10;
        float s = bias[cl];
#pragma unroll
        for (int w = 0; w < 7; ++w) s += part[w][im][cl];
        logits[im][cl] = s;
    }
    __syncthreads();

    // ---- log_softmax: 40 threads, redundant per-image lse ----
    if (tid < 40) {
        const int im = tid / 10, cl = tid - (tid / 10) * 10;
        const int img = blockIdx.x * 4 + im;
        if (img < B) {
            float m = logits[im][0];
#pragma unroll
            for (int j = 1; j < 10; ++j) m = fmaxf(m, logits[im][j]);
            float s = 0.f;
#pragma unroll
            for (int j = 0; j < 10; ++j) s += __expf(logits[im][j] - m);
            out[(size_t)img * 10 + cl] = logits[im][cl] - m - __logf(s);
        }
    }
}

extern "C" void kernel_launch(void* const* d_in, const int* in_sizes, int n_in,
                              void* d_out, int out_size, void* d_ws, size_t ws_size,
                              hipStream_t stream) {
    const float* x    = (const float*)d_in[0];
    const float* wts  = (const float*)d_in[1];
    const float* W    = (const float*)d_in[2];
    const float* bias = (const float*)d_in[3];
    float* out        = (float*)d_out;

    const int B = in_sizes[0] / 784;
    const int blocks = (B + 3) / 4;   // 4 images/block, 7 waves/block
    quanv_pair_kernel<<<blocks, 448, 0, stream>>>(x, wts, W, bias, out, B);
}

// Round 10
// 17.819 us; speedup vs baseline: 1.4918x; 1.1158x over previous
//
#include <hip/hip_runtime.h>
#include <math.h>

// Quanvolution via Pauli back-propagation (derivation R1, validated R1-R8):
//  alpha_q = theta_q + w0_q; A..D = cos(alpha_q), a..d = sin(alpha_q):
//   z0 = K0*A  + K1*ab
//   z1 = K2*B  + K3*A*bc + K4*ac
//   z2 = K5*AC + K6*B*cd + K7*A*bd + K8*ab*C + K9*ad
//   z3 = L1*BD + L2*AC*d + L3*Bc + L4*Ab*cD + L5*Ab + L6*ab*Cd + L7*ac*D + L8*a
//
// R9 = R6 structure (best: 18.73) + R8 load shape:
//  256-thread block, 8 images; wave = (img-group g, K-half h); each wave does
//  4 images x 49 horizontal patch-PAIRS in ONE pass (lane<49 active):
//  x = 2 aligned float4 loads per image (was 4 float2), W = 2 contiguous
//  float4 per class broadcast-reused by 4 images. Tail identical to R6.
#define INV2PI 0.15915494309189535f

__device__ __forceinline__ float rfl(float v) {
    return __int_as_float(__builtin_amdgcn_readfirstlane(__float_as_int(v)));
}

__global__ __launch_bounds__(256, 4) void quanv_r9_kernel(
    const float* __restrict__ x,     // [B, 784]
    const float* __restrict__ wts,   // [2, 4]
    const float* __restrict__ W,     // [10, 784]
    const float* __restrict__ bias,  // [10]
    float* __restrict__ out,         // [B, 10]
    int B)
{
    __shared__ float part[4][8][40];   // [wave][octet][im*10+cl]
    __shared__ float logits[8][10];
    __shared__ float lsev[8];

    const int tid   = threadIdx.x;
    const int wave  = tid >> 6, lane = tid & 63;
    const int group = wave >> 1;          // image sub-set 0,1
    const int half  = wave & 1;           // pair-half 0,1
    const int imgb  = blockIdx.x * 8 + group * 4;

    // ---- pair geometry; issue x loads as early as possible ----
    const bool act = (lane < 49);
    const int q  = half * 49 + lane;      // pair 0..97
    const int pi = q / 7;                 // patch row 0..13
    const int pj = q - pi * 7;            // pair col 0..6
    const int xoff = pi * 56 + pj * 4;    // row 2pi, col 4pj (float4-aligned)

    float4 xt[4], xb[4];
#pragma unroll
    for (int im = 0; im < 4; ++im) {
        xt[im] = make_float4(0.f, 0.f, 0.f, 0.f);
        xb[im] = xt[im];
    }
    if (act) {
#pragma unroll
        for (int im = 0; im < 4; ++im) {
            const float* xp = x + (size_t)(imgb + im) * 784 + xoff;
            xt[im] = *(const float4*)xp;          // row 2pi
            xb[im] = *(const float4*)(xp + 28);   // row 2pi+1
        }
    }

    // ---- uniform constants, pinned to SGPRs (hides x latency) ----
    float w0r[4], cw1[4], sw1[4];
#pragma unroll
    for (int qq = 0; qq < 4; ++qq) {
        w0r[qq] = rfl(wts[qq] * INV2PI);
        float r = wts[4 + qq] * INV2PI;
        r -= floorf(r);
        cw1[qq] = __builtin_amdgcn_cosf(r);
        sw1[qq] = __builtin_amdgcn_sinf(r);
    }
    const float cc  = cw1[0]*cw1[1], cs = cw1[0]*sw1[1];
    const float sc  = sw1[0]*cw1[1], ss = sw1[0]*sw1[1];
    const float ccc = cc*cw1[2], ccs = cc*sw1[2], csc = cs*cw1[2], css = cs*sw1[2];
    const float scc = sc*cw1[2], ssc = ss*cw1[2], sss = ss*sw1[2];
    const float K0 = rfl(cw1[0]),       K1 = rfl(-sw1[0]);
    const float K2 = rfl(cc),           K3 = rfl(-cs),          K4 = rfl(ss);
    const float K5 = rfl(ccc),          K6 = rfl(-ccs),         K7 = rfl(css);
    const float K8 = rfl(-scc),         K9 = rfl(-sss);
    const float L1 = rfl(ccc*cw1[3]),   L2 = rfl(-ccc*sw1[3]);
    const float L3 = rfl(ccs*sw1[3]),   L4 = rfl(-csc*cw1[3]);
    const float L5 = rfl(-css*sw1[3]),  L6 = rfl(scc*sw1[3]);
    const float L7 = rfl(ssc*cw1[3]),   L8 = rfl(sss*sw1[3]);

    // ---- compute z for 4 images x 2 patches ----
    float z[4][2][4];
#pragma unroll
    for (int im = 0; im < 4; ++im) {
#pragma unroll
        for (int h2 = 0; h2 < 2; ++h2) {
            const float t0 = h2 ? xt[im].z : xt[im].x;
            const float t1 = h2 ? xt[im].w : xt[im].y;
            const float t2 = h2 ? xb[im].z : xb[im].x;
            const float t3 = h2 ? xb[im].w : xb[im].y;

            float r;
            r = fmaf(t0, INV2PI, w0r[0]); r -= floorf(r);
            const float a  = __builtin_amdgcn_sinf(r), A  = __builtin_amdgcn_cosf(r);
            r = fmaf(t1, INV2PI, w0r[1]); r -= floorf(r);
            const float b  = __builtin_amdgcn_sinf(r), Bv = __builtin_amdgcn_cosf(r);
            r = fmaf(t2, INV2PI, w0r[2]); r -= floorf(r);
            const float c  = __builtin_amdgcn_sinf(r), C  = __builtin_amdgcn_cosf(r);
            r = fmaf(t3, INV2PI, w0r[3]); r -= floorf(r);
            const float d  = __builtin_amdgcn_sinf(r), D  = __builtin_amdgcn_cosf(r);

            const float ab=a*b, bc=b*c, ac=a*c, cd=c*d, bd=b*d, ad=a*d;
            const float AC=A*C, Ab=A*b, Bc=Bv*c, BD=Bv*D, cD=c*D, Cd=C*d;

            z[im][h2][0] = fmaf(K0, A,  K1*ab);
            z[im][h2][1] = fmaf(K2, Bv, fmaf(K3, A*bc, K4*ac));
            z[im][h2][2] = fmaf(K5, AC, fmaf(K6, Bv*cd,
                           fmaf(K7, A*bd, fmaf(K8, ab*C, K9*ad))));
            z[im][h2][3] = fmaf(L1, BD, fmaf(L2, AC*d, fmaf(L3, Bc,
                           fmaf(L4, Ab*cD, fmaf(L5, Ab, fmaf(L6, ab*Cd,
                           fmaf(L7, ac*D, L8*a)))))));
        }
    }

    // ---- GEMM: 2 contiguous W float4 per class, reused by 4 images ----
    float acc[4][10];
#pragma unroll
    for (int im = 0; im < 4; ++im)
#pragma unroll
        for (int cl = 0; cl < 10; ++cl) acc[im][cl] = 0.f;

    if (act) {
        const int kL = pi * 56 + pj * 8;   // k-offset of patch (pi, 2pj)
#pragma unroll
        for (int cl = 0; cl < 10; ++cl) {
            const float* wp = W + cl * 784 + kL;
            const float4 wvL = *(const float4*)wp;
            const float4 wvR = *(const float4*)(wp + 4);
#pragma unroll
            for (int im = 0; im < 4; ++im)
                acc[im][cl] = fmaf(z[im][0][0], wvL.x, fmaf(z[im][0][1], wvL.y,
                              fmaf(z[im][0][2], wvL.z, fmaf(z[im][0][3], wvL.w,
                              fmaf(z[im][1][0], wvR.x, fmaf(z[im][1][1], wvR.y,
                              fmaf(z[im][1][2], wvR.z, fmaf(z[im][1][3], wvR.w,
                              acc[im][cl]))))))));
        }
    }

    // ---- 3-level butterfly within octets, octet sums to LDS (R6 tail) ----
#pragma unroll
    for (int im = 0; im < 4; ++im)
#pragma unroll
        for (int cl = 0; cl < 10; ++cl) {
            float v = acc[im][cl];
            v += __shfl_xor(v, 1, 64);
            v += __shfl_xor(v, 2, 64);
            v += __shfl_xor(v, 4, 64);
            if ((lane & 7) == 0) part[wave][lane >> 3][im * 10 + cl] = v;
        }
    __syncthreads();

    // ---- cross-octet + cross-wave: 80 threads, one (group,im,cl) each ----
    if (tid < 80) {
        const int g  = tid / 40;
        const int vv = tid - g * 40;
        const int im = vv / 10, cl = vv - im * 10;
        float s = 0.f;
#pragma unroll
        for (int l = 0; l < 8; ++l)
            s += part[2 * g][l][vv] + part[2 * g + 1][l][vv];
        logits[g * 4 + im][cl] = s + bias[cl];
    }
    __syncthreads();

    // ---- per-image lse (8 threads) ----
    if (tid < 8) {
        if (blockIdx.x * 8 + tid < B) {
            float m = logits[tid][0];
#pragma unroll
            for (int cl = 1; cl < 10; ++cl) m = fmaxf(m, logits[tid][cl]);
            float s = 0.f;
#pragma unroll
            for (int cl = 0; cl < 10; ++cl) s += __expf(logits[tid][cl] - m);
            lsev[tid] = m + __logf(s);
        }
    }
    __syncthreads();

    // ---- store ----
    if (tid < 80) {
        const int imloc = tid / 10, cl = tid - (tid / 10) * 10;
        const int img = blockIdx.x * 8 + imloc;
        if (img < B)
            out[(size_t)img * 10 + cl] = logits[imloc][cl] - lsev[imloc];
    }
}

extern "C" void kernel_launch(void* const* d_in, const int* in_sizes, int n_in,
                              void* d_out, int out_size, void* d_ws, size_t ws_size,
                              hipStream_t stream) {
    const float* x    = (const float*)d_in[0];
    const float* wts  = (const float*)d_in[1];
    const float* W    = (const float*)d_in[2];
    const float* bias = (const float*)d_in[3];
    float* out        = (float*)d_out;

    const int B = in_sizes[0] / 784;
    const int blocks = (B + 7) / 8;   // 8 images/block
    quanv_r9_kernel<<<blocks, 256, 0, stream>>>(x, wts, W, bias, out, B);
}